// Round 1
// baseline (188.810 us; speedup 1.0000x reference)
//
#include <hip/hip_runtime.h>
#include <math.h>

#define BLOCK 256
#define VEC   4
#define TILE  (BLOCK * VEC)   // 1024 elements per block
#define KW    5
// conv pad = 2 each; two stacked convs -> x halo = 4, h halo = 2

__global__ __launch_bounds__(BLOCK) void wav_attn_kernel(
    const float* __restrict__ x,
    const float* __restrict__ w1,
    const float* __restrict__ b1,
    const float* __restrict__ w2,
    const float* __restrict__ b2,
    float* __restrict__ out,
    int C, int L)
{
    __shared__ float sx[TILE + 8];   // x[t0-4 .. t0+TILE+3]
    __shared__ float sh[TILE + 4];   // h[t0-2 .. t0+TILE+1]

    const int row = blockIdx.y;          // b*C + c
    const int c   = row % C;
    const long long base = (long long)row * L;
    const int t0  = blockIdx.x * TILE;
    const int tid = threadIdx.x;

    // per-channel weights: block-uniform address -> scalar loads
    float W1[KW], W2[KW];
    #pragma unroll
    for (int k = 0; k < KW; ++k) {
        W1[k] = w1[c * KW + k];
        W2[k] = w2[c * KW + k];
    }
    const float B1 = b1[c];
    const float B2 = b2[c];

    // ---- stage x tile (vectorized body) ----
    {
        int j = tid * VEC;               // 0..TILE-4
        int g = t0 + j;
        float4 v;
        if (g + 3 < L) {
            v = *reinterpret_cast<const float4*>(x + base + g);
        } else {
            float tmp[4] = {0.f, 0.f, 0.f, 0.f};
            #pragma unroll
            for (int e = 0; e < 4; ++e)
                if (g + e < L) tmp[e] = x[base + g + e];
            v = make_float4(tmp[0], tmp[1], tmp[2], tmp[3]);
        }
        *reinterpret_cast<float4*>(&sx[4 + j]) = v;
    }
    // halos (8 scalar loads per block)
    if (tid < 4) {
        int gg = t0 - 4 + tid;
        sx[tid] = (gg >= 0 && gg < L) ? x[base + gg] : 0.f;
    } else if (tid < 8) {
        int e  = tid - 4;
        int gg = t0 + TILE + e;
        sx[TILE + 4 + e] = (gg < L) ? x[base + gg] : 0.f;
    }
    __syncthreads();

    // ---- h = LeakyReLU(conv1(x)) with zero outside [0,L) ----
    // sh[j] corresponds to position p = t0 - 2 + j
    for (int j = tid; j < TILE + 4; j += BLOCK) {
        int p = t0 - 2 + j;
        float acc = B1;
        #pragma unroll
        for (int k = 0; k < KW; ++k)
            acc = fmaf(W1[k], sx[j + k], acc);      // x[p+k-2] = sx[j+k]
        acc = (acc >= 0.f) ? acc : 0.01f * acc;
        // conv2 zero-pads h outside [0,L): must be 0, NOT leaky(B1)
        sh[j] = (p >= 0 && p < L) ? acc : 0.f;
    }
    __syncthreads();

    // ---- out = x * sigmoid(conv2(h)) ----
    {
        int m = tid * VEC;
        int i = t0 + m;
        if (i < L) {
            float res[4];
            #pragma unroll
            for (int e = 0; e < 4; ++e) {
                float z = B2;
                #pragma unroll
                for (int k = 0; k < KW; ++k)
                    z = fmaf(W2[k], sh[m + e + k], z);  // h[i+e+k-2] = sh[m+e+k]
                float s = 1.f / (1.f + __expf(-z));
                res[e] = sx[4 + m + e] * s;
            }
            if (i + 3 < L) {
                *reinterpret_cast<float4*>(out + base + i) =
                    make_float4(res[0], res[1], res[2], res[3]);
            } else {
                #pragma unroll
                for (int e = 0; e < 4; ++e)
                    if (i + e < L) out[base + i + e] = res[e];
            }
        }
    }
}

extern "C" void kernel_launch(void* const* d_in, const int* in_sizes, int n_in,
                              void* d_out, int out_size, void* d_ws, size_t ws_size,
                              hipStream_t stream) {
    const float* x  = (const float*)d_in[0];
    const float* w1 = (const float*)d_in[1];
    const float* b1 = (const float*)d_in[2];
    const float* w2 = (const float*)d_in[3];
    const float* b2 = (const float*)d_in[4];
    float* out = (float*)d_out;

    const int C = in_sizes[2];               // 20
    const int B = 128;
    const int L = in_sizes[0] / (B * C);     // 10000

    dim3 grid((L + TILE - 1) / TILE, B * C); // 10 x 2560 blocks
    wav_attn_kernel<<<grid, BLOCK, 0, stream>>>(x, w1, b1, w2, b2, out, C, L);
}

// Round 2
// 180.872 us; speedup vs baseline: 1.0439x; 1.0439x over previous
//
#include <hip/hip_runtime.h>
#include <math.h>

#define BLOCK 256
#define VEC   4
#define TILE  (BLOCK * VEC)   // 1024 elements per block
#define KW    5
// conv pad = 2 each; two stacked convs -> receptive field of out[i] is x[i-4 .. i+4]
// Each thread computes 4 outputs from x[i-4 .. i+7] (three aligned float4 loads),
// recomputing h[i-2 .. i+5] in registers. No LDS, no barriers.

__global__ __launch_bounds__(BLOCK) void wav_attn_kernel(
    const float* __restrict__ x,
    const float* __restrict__ w1,
    const float* __restrict__ b1,
    const float* __restrict__ w2,
    const float* __restrict__ b2,
    float* __restrict__ out,
    int C, int L)
{
    const int row = blockIdx.y;          // b*C + c
    const int c   = row % C;
    const long long base = (long long)row * L;
    const int i   = blockIdx.x * TILE + threadIdx.x * VEC;
    if (i >= L) return;

    // per-channel weights: block-uniform address -> scalar (s_load) path
    float W1[KW], W2[KW];
    #pragma unroll
    for (int k = 0; k < KW; ++k) {
        W1[k] = w1[c * KW + k];
        W2[k] = w2[c * KW + k];
    }
    const float B1 = b1[c];
    const float B2 = b2[c];

    // ---- load x[i-4 .. i+7] into a[0..11] ----
    float a[12];
    if (i >= 4 && i + 7 < L) {
        // i is a multiple of 4 -> all three loads are 16B-aligned
        float4 v0 = *reinterpret_cast<const float4*>(x + base + i - 4);
        float4 v1 = *reinterpret_cast<const float4*>(x + base + i);
        float4 v2 = *reinterpret_cast<const float4*>(x + base + i + 4);
        a[0] = v0.x; a[1] = v0.y; a[2]  = v0.z; a[3]  = v0.w;
        a[4] = v1.x; a[5] = v1.y; a[6]  = v1.z; a[7]  = v1.w;
        a[8] = v2.x; a[9] = v2.y; a[10] = v2.z; a[11] = v2.w;
    } else {
        #pragma unroll
        for (int e = 0; e < 12; ++e) {
            int g = i - 4 + e;
            a[e] = (g >= 0 && g < L) ? x[base + g] : 0.f;
        }
    }

    // ---- h[j] = LeakyReLU(conv1)(x) at position p = i + j - 2, j = 0..7 ----
    // conv2's zero-padding applies to h: force 0 outside [0, L)
    float h[8];
    #pragma unroll
    for (int j = 0; j < 8; ++j) {
        int p = i + j - 2;
        float acc = B1;
        #pragma unroll
        for (int k = 0; k < KW; ++k)
            acc = fmaf(W1[k], a[j + k], acc);   // x[p+k-2] = a[j+k]
        acc = (acc >= 0.f) ? acc : 0.01f * acc;
        h[j] = (p >= 0 && p < L) ? acc : 0.f;
    }

    // ---- out[i+e] = x[i+e] * sigmoid(conv2(h)) ----
    float res[4];
    #pragma unroll
    for (int e = 0; e < 4; ++e) {
        float z = B2;
        #pragma unroll
        for (int k = 0; k < KW; ++k)
            z = fmaf(W2[k], h[e + k], z);       // h[i+e+k-2] = h[e+k]
        float s = __builtin_amdgcn_rcpf(1.f + __expf(-z));
        res[e] = a[4 + e] * s;
    }

    if (i + 3 < L) {
        *reinterpret_cast<float4*>(out + base + i) =
            make_float4(res[0], res[1], res[2], res[3]);
    } else {
        #pragma unroll
        for (int e = 0; e < 4; ++e)
            if (i + e < L) out[base + i + e] = res[e];
    }
}

extern "C" void kernel_launch(void* const* d_in, const int* in_sizes, int n_in,
                              void* d_out, int out_size, void* d_ws, size_t ws_size,
                              hipStream_t stream) {
    const float* x  = (const float*)d_in[0];
    const float* w1 = (const float*)d_in[1];
    const float* b1 = (const float*)d_in[2];
    const float* w2 = (const float*)d_in[3];
    const float* b2 = (const float*)d_in[4];
    float* out = (float*)d_out;

    const int C = in_sizes[2];               // 20
    const int B = 128;
    const int L = in_sizes[0] / (B * C);     // 10000

    dim3 grid((L + TILE - 1) / TILE, B * C); // 10 x 2560 blocks
    wav_attn_kernel<<<grid, BLOCK, 0, stream>>>(x, w1, b1, w2, b2, out, C, L);
}